// Round 8
// baseline (49.079 us; speedup 1.0000x reference)
//
#include <hip/hip_runtime.h>
#include <math.h>

// B=4, 3 anchors, 85 ch. Layers g=10/20/40 -> P=300/1200/4800 pos/img.
// Global rows: l0 [0,1200), l1 [1200,6000), l2 [6000,25200). NROWS=25200.
//
// ws layout (every slot that is read is re-written every call):
//   flag  float[25200]  @ 0       obj per row, FULL overwrite each call
//   bbox  float4[25200] @ 100864  (minx,miny,maxx,maxy); written iff flag!=0, read iff flag!=0
//   partials float[396] @ 504064  every block writes its slot each call
//   done  int           @ 505664  zeroed by k_compact each call

#define NBLK 396
#define SCAP 512

__device__ __constant__ float c_anc[3][3][2] = {
  {{116.f, 90.f}, {156.f, 198.f}, {373.f, 326.f}},
  {{ 30.f, 61.f}, { 62.f,  45.f}, { 59.f, 119.f}},
  {{ 10.f, 13.f}, { 16.f,  30.f}, { 33.f,  23.f}}};

__device__ __forceinline__ float bce_f(float label, float logit) {
    return fmaxf(logit, 0.0f) - logit * label + log1pf(expf(-fabsf(logit)));
}

__global__ __launch_bounds__(256) void k_compact(
    const float* __restrict__ t0, const float* __restrict__ t1, const float* __restrict__ t2,
    float* __restrict__ flag, float4* __restrict__ bbox, int* __restrict__ done)
{
    int gid = blockIdx.x * 256 + threadIdx.x;
    if (gid == 0) *done = 0;                       // ordered before k_main by dispatch boundary
    if (gid >= 25200) return;
    const float* t; int idx;
    if (gid < 1200)      { t = t0; idx = gid;        }
    else if (gid < 6000) { t = t1; idx = gid - 1200; }
    else                 { t = t2; idx = gid - 6000; }
    const float* tp = t + (size_t)idx * 85;
    float obj = tp[4];
    flag[gid] = obj;                               // deterministic full overwrite
    if (obj != 0.0f) {
        float tx = tp[0], ty = tp[1], tw = tp[2], th = tp[3];
        bbox[gid] = make_float4(tx - tw * 0.5f, ty - th * 0.5f,
                                tx + tw * 0.5f, ty + th * 0.5f);
    }
}

template<int P, int G>
__device__ __forceinline__ float layer_block(
    const float* __restrict__ t, const float* __restrict__ y,
    int img, int chunk, int lbase, const float (*anc)[2],
    const float* __restrict__ flag, const float4* __restrict__ bbox,
    float4* sbox, int* scount)
{
    const int tid = threadIdx.x;                   // 64-thread block == one wave
    const int gbase = lbase + img * P;             // global row of this image's pos 0
    const int rbase = img * P;                     // row base within this layer

    // ---- prefetch my position's operands (latency hides under phase A) ----
    int pos = chunk * 64 + tid;
    bool valid = pos < P;
    int ppre = valid ? pos : 0;
    const float* yp = y + (size_t)(rbase + ppre) * 85;
    float q0 = yp[0], q1 = yp[1], q2 = yp[2], q3 = yp[3], q4 = yp[4];
    float obj = flag[gbase + ppre];                // coalesced 4B
    if (!valid) obj = 0.0f;

    // ---- phase A: stage image's target boxes from flag (coalesced f4) + bbox gather ----
    if (tid == 0) *scount = 0;
    __syncthreads();
    const float4* fimg4 = (const float4*)(flag + gbase);   // gbase%4==0 all layers
    for (int k4 = tid; k4 < P / 4; k4 += 64) {
        float4 fv = fimg4[k4];
        float fs[4] = {fv.x, fv.y, fv.z, fv.w};
        #pragma unroll
        for (int c = 0; c < 4; ++c) {
            if (fs[c] != 0.0f) {
                int off = atomicAdd(scount, 1);    // LDS-local, zeroed above
                if (off < SCAP) sbox[off] = bbox[gbase + 4 * k4 + c];
            }
        }
    }
    __syncthreads();
    int cnt = *scount; if (cnt > SCAP) cnt = SCAP;
    int cntPad = (cnt + 7) & ~7;                   // pad boxes are (0,0,0,0): margin=-pa<0
    for (int k = cnt + tid; k < cntPad; k += 64)
        sbox[k] = make_float4(0.f, 0.f, 0.f, 0.f);
    __syncthreads();

    // ---- phase B: conf term; division-free ignore test ----
    // iou>=0.5  <=>  3*inter >= p_area + t_area   (union = pa+ta-inter > 0)
    float acc = 0.0f;
    if (valid) {
        int a = pos % 3, cell = pos / 3;
        int j = cell % G, i = cell / G;
        float aw = anc[a][0], ah = anc[a][1];
        float gi = (float)G;

        float px = (1.0f / (1.0f + expf(-q0)) + (float)j) / gi;
        float py = (1.0f / (1.0f + expf(-q1)) + (float)i) / gi;
        float pw = expf(q2) * aw * (1.0f / 320.0f);
        float ph = expf(q3) * ah * (1.0f / 320.0f);
        float phx = pw * 0.5f, phy = ph * 0.5f;
        float pminx = px - phx, pmaxx = px + phx;
        float pminy = py - phy, pmaxy = py + phy;
        float pa = pw * ph;

        float m = -1.0f;                            // max margin; <0 => ignore
        for (int k0 = 0; k0 < cntPad; k0 += 8) {
            float mm[8];
            #pragma unroll
            for (int u = 0; u < 8; ++u) {
                float4 tb = sbox[k0 + u];           // minx,miny,maxx,maxy (LDS broadcast)
                float wx = fminf(pmaxx, tb.z) - fmaxf(pminx, tb.x);
                float wy = fminf(pmaxy, tb.w) - fmaxf(pminy, tb.y);
                wx = fmaxf(wx, 0.0f);
                wy = fmaxf(wy, 0.0f);
                float inter = wx * wy;
                float ta = (tb.z - tb.x) * (tb.w - tb.y);
                mm[u] = 3.0f * inter - pa - ta;
            }
            float a0 = fmaxf(mm[0], mm[1]), a1 = fmaxf(mm[2], mm[3]);
            float a2 = fmaxf(mm[4], mm[5]), a3 = fmaxf(mm[6], mm[7]);
            m = fmaxf(m, fmaxf(fmaxf(a0, a1), fmaxf(a2, a3)));
        }
        float ignore = (m < 0.0f) ? 1.0f : 0.0f;
        float bce_c = fmaxf(q4, 0.0f) - q4 * obj + log1pf(expf(-fabsf(q4)));
        acc = (obj + (1.0f - obj) * ignore) * bce_c;   // gate==1 for positives
    }

    // ---- phase C: positives in this wave, whole-wave per-channel (coalesced) ----
    const float* tslab = t + (size_t)rbase * 85;
    const float* yslab = y + (size_t)rbase * 85;
    unsigned long long mb = __ballot(valid && obj != 0.0f);
    int lane = tid;
    int waveBase = chunk * 64;
    while (mb) {
        int b = __ffsll(mb) - 1; mb &= mb - 1;
        int ppos = waveBase + b;
        const float* tp = tslab + (size_t)ppos * 85;
        const float* ypp = yslab + (size_t)ppos * 85;
        float tv1 = tp[lane], yv1 = ypp[lane];          // ch 0..63
        bool has2 = lane < 21;
        float tv2 = 0.f, yv2 = 0.f;
        if (has2) { tv2 = tp[lane + 64]; yv2 = ypp[lane + 64]; }  // ch 64..84

        float tw = __shfl(tv1, 2, 64);
        float th = __shfl(tv1, 3, 64);
        float bs = 2.0f - tw * th;
        int a = ppos % 3, cell = ppos / 3;
        int jj = cell % G, ii = cell / G;
        float aw = anc[a][0], ah = anc[a][1];

        float term;
        if (lane == 0)      term = bs * bce_f(tv1 * (float)G - (float)jj, yv1);
        else if (lane == 1) term = bs * bce_f(tv1 * (float)G - (float)ii, yv1);
        else if (lane == 2) { float d = logf(tv1 * 320.0f / aw) - yv1; term = bs * 0.5f * d * d; }
        else if (lane == 3) { float d = logf(tv1 * 320.0f / ah) - yv1; term = bs * 0.5f * d * d; }
        else if (lane == 4) term = 0.0f;               // conf for positives already in phase B
        else                term = bce_f(tv1, yv1);    // cls 5..63
        if (has2) term += bce_f(tv2, yv2);             // cls 64..84
        acc += term;
    }
    return acc;
}

__global__ __launch_bounds__(64) void k_main(
    const float* __restrict__ t0, const float* __restrict__ y0,
    const float* __restrict__ t1, const float* __restrict__ y1,
    const float* __restrict__ t2, const float* __restrict__ y2,
    const float* __restrict__ flag, const float4* __restrict__ bbox,
    float* __restrict__ partials, int* __restrict__ done,
    float* __restrict__ out)
{
    __shared__ float4 sbox[SCAP];
    __shared__ int scount;
    int blk = blockIdx.x;

    float acc;
    if (blk < 20)      acc = layer_block< 300, 10>(t0, y0, blk / 5,  blk % 5,  0,    c_anc[0], flag, bbox, sbox, &scount);
    else if (blk < 96) { int r = blk - 20; acc = layer_block<1200, 20>(t1, y1, r / 19, r % 19, 1200, c_anc[1], flag, bbox, sbox, &scount); }
    else               { int r = blk - 96; acc = layer_block<4800, 40>(t2, y2, r / 75, r % 75, 6000, c_anc[2], flag, bbox, sbox, &scount); }

    // single-wave block reduce
    float v = acc;
    #pragma unroll
    for (int o = 32; o > 0; o >>= 1) v += __shfl_down(v, o, 64);

    // last-block-done finalize (done zeroed by k_compact this call)
    int lane = threadIdx.x;
    int old = 0;
    if (lane == 0) {
        __hip_atomic_store(&partials[blk], v * 0.25f, __ATOMIC_RELAXED, __HIP_MEMORY_SCOPE_AGENT);
        old = __hip_atomic_fetch_add(done, 1, __ATOMIC_ACQ_REL, __HIP_MEMORY_SCOPE_AGENT);
    }
    old = __shfl(old, 0, 64);
    if (old == NBLK - 1) {
        float s = 0.0f;
        for (int r = lane; r < NBLK; r += 64)
            s += __hip_atomic_load(&partials[r], __ATOMIC_RELAXED, __HIP_MEMORY_SCOPE_AGENT);
        #pragma unroll
        for (int o = 32; o > 0; o >>= 1) s += __shfl_down(s, o, 64);
        if (lane == 0) out[0] = s;
    }
}

extern "C" void kernel_launch(void* const* d_in, const int* in_sizes, int n_in,
                              void* d_out, int out_size, void* d_ws, size_t ws_size,
                              hipStream_t stream) {
    // setup_inputs dict order: t0, y0, t1, y1, t2, y2
    const float* t0 = (const float*)d_in[0];
    const float* y0 = (const float*)d_in[1];
    const float* t1 = (const float*)d_in[2];
    const float* y1 = (const float*)d_in[3];
    const float* t2 = (const float*)d_in[4];
    const float* y2 = (const float*)d_in[5];

    float*  flag     = (float*)d_ws;
    float4* bbox     = (float4*)((char*)d_ws + 100864);
    float*  partials = (float*)((char*)d_ws + 504064);
    int*    done     = (int*)((char*)d_ws + 505664);
    float*  out      = (float*)d_out;

    k_compact<<<99, 256, 0, stream>>>(t0, t1, t2, flag, bbox, done);
    k_main<<<NBLK, 64, 0, stream>>>(t0, y0, t1, y1, t2, y2, flag, bbox, partials, done, out);
}

// Round 9
// 34.244 us; speedup vs baseline: 1.4332x; 1.4332x over previous
//
#include <hip/hip_runtime.h>
#include <math.h>

// B=4, 3 anchors, 85 ch. Layers g=10/20/40 -> P=300/1200/4800 pos/img.
// k_main grid: one (img, 256-pos chunk) per block:
//   l0: 2/img -> blk 0..7   l1: 5/img -> blk 8..27   l2: 19/img -> blk 28..103
#define NBLK 104
#define SCAP 512
#define CAP0 64
#define CAP1 128
#define CAP2 512
// box slots: l0 img*64 [0,256); l1 256+img*128 [256,768); l2 768+img*512 [768,2816)
// ws: counts int[16] @0 ; done int @64 ; boxes float4[2816] @128 ;
//     partials float[104] @45184

__device__ __constant__ float c_anc[3][3][2] = {
  {{116.f, 90.f}, {156.f, 198.f}, {373.f, 326.f}},
  {{ 30.f, 61.f}, { 62.f,  45.f}, { 59.f, 119.f}},
  {{ 10.f, 13.f}, { 16.f,  30.f}, { 33.f,  23.f}}};

__device__ __forceinline__ float bce_f(float label, float logit) {
    return fmaxf(logit, 0.0f) - logit * label + log1pf(expf(-fabsf(logit)));
}

__global__ void k_init(int* __restrict__ counts, int* __restrict__ done) {
    if (threadIdx.x < 16) counts[threadIdx.x] = 0;
    if (threadIdx.x == 16) *done = 0;
}

// dense per-(l,img) min/max box lists; per-thread atomic append (12 counters,
// ~42 serialized adds per counter ~ 0.6 us)
__global__ __launch_bounds__(256) void k_compact(
    const float* __restrict__ t0, const float* __restrict__ t1, const float* __restrict__ t2,
    int* __restrict__ counts, float4* __restrict__ boxes)
{
    int gid = blockIdx.x * 256 + threadIdx.x;
    if (gid >= 25200) return;
    const float* t; int l, idx, P, cap, base;
    if (gid < 1200)      { l = 0; idx = gid;        t = t0; P = 300;  cap = CAP0; base = 0;   }
    else if (gid < 6000) { l = 1; idx = gid - 1200; t = t1; P = 1200; cap = CAP1; base = 256; }
    else                 { l = 2; idx = gid - 6000; t = t2; P = 4800; cap = CAP2; base = 768; }
    const float* tp = t + (size_t)idx * 85;
    float obj = tp[4];
    if (obj != 0.0f) {
        int img = idx / P;
        int slotBase = base + img * cap;
        int s = atomicAdd(&counts[l * 4 + img], 1);
        if (s < cap) {
            float tx = tp[0], ty = tp[1], tw = tp[2], th = tp[3];
            boxes[slotBase + s] = make_float4(tx - tw * 0.5f, ty - th * 0.5f,
                                              tx + tw * 0.5f, ty + th * 0.5f);
        }
    }
}

template<int P, int G>
__device__ __forceinline__ float layer_block(
    const float* __restrict__ t, const float* __restrict__ y,
    int img, int chunk, int cap, int slotBase, const float (*anc)[2],
    const int* __restrict__ counts, const float4* __restrict__ boxes,
    float4* sbox, int lw)
{
    const int tid = threadIdx.x;
    const float* tslab = t + (size_t)img * P * 85;
    const float* yslab = y + (size_t)img * P * 85;

    // ---- prefetch this thread's operands (latency hides under phase A) ----
    int pos = chunk * 256 + tid;
    bool valid = pos < P;
    int ppre = valid ? pos : 0;
    const float* yp = yslab + (size_t)ppre * 85;
    float q0 = yp[0], q1 = yp[1], q2 = yp[2], q3 = yp[3], q4 = yp[4];
    float obj = tslab[(size_t)ppre * 85 + 4];
    if (!valid) obj = 0.0f;

    // ---- phase A: dense box list -> LDS (<=2 coalesced rounds) ----
    int cnt = counts[lw];                          // uniform load, broadcast
    if (cnt > cap) cnt = cap;
    int cntPad = (cnt + 7) & ~7;                   // pad: margin = -pa < 0, harmless
    for (int k = tid; k < cntPad; k += 256)
        sbox[k] = (k < cnt) ? boxes[slotBase + k]
                            : make_float4(0.f, 0.f, 0.f, 0.f);
    __syncthreads();

    // ---- phase B: conf term; division-free ignore (iou>=0.5 <=> 3*inter>=pa+ta) ----
    float acc = 0.0f;
    if (valid) {
        int a = pos % 3, cell = pos / 3;
        int j = cell % G, i = cell / G;
        float aw = anc[a][0], ah = anc[a][1];
        float gi = (float)G;

        float px = (1.0f / (1.0f + expf(-q0)) + (float)j) / gi;
        float py = (1.0f / (1.0f + expf(-q1)) + (float)i) / gi;
        float pw = expf(q2) * aw * (1.0f / 320.0f);
        float ph = expf(q3) * ah * (1.0f / 320.0f);
        float phx = pw * 0.5f, phy = ph * 0.5f;
        float pminx = px - phx, pmaxx = px + phx;
        float pminy = py - phy, pmaxy = py + phy;
        float pa = pw * ph;

        float m = -1.0f;                            // max margin; <0 => ignore
        for (int k0 = 0; k0 < cntPad; k0 += 8) {
            float mm[8];
            #pragma unroll
            for (int u = 0; u < 8; ++u) {
                float4 tb = sbox[k0 + u];           // (minx,miny,maxx,maxy)
                float wx = fminf(pmaxx, tb.z) - fmaxf(pminx, tb.x);
                float wy = fminf(pmaxy, tb.w) - fmaxf(pminy, tb.y);
                wx = fmaxf(wx, 0.0f);
                wy = fmaxf(wy, 0.0f);
                float inter = wx * wy;
                float ta = (tb.z - tb.x) * (tb.w - tb.y);
                mm[u] = 3.0f * inter - pa - ta;
            }
            float a0 = fmaxf(mm[0], mm[1]), a1 = fmaxf(mm[2], mm[3]);
            float a2 = fmaxf(mm[4], mm[5]), a3 = fmaxf(mm[6], mm[7]);
            m = fmaxf(m, fmaxf(fmaxf(a0, a1), fmaxf(a2, a3)));
        }
        float ignore = (m < 0.0f) ? 1.0f : 0.0f;
        float bce_c = fmaxf(q4, 0.0f) - q4 * obj + log1pf(expf(-fabsf(q4)));
        acc = (obj + (1.0f - obj) * ignore) * bce_c;   // gate==1 for positives
    }

    // ---- phase C: positives, whole-wave per-channel (coalesced rows) ----
    unsigned long long mb = __ballot(valid && obj != 0.0f);
    int lane = tid & 63;
    int waveBase = chunk * 256 + (tid & ~63);
    while (mb) {
        int b = __ffsll(mb) - 1; mb &= mb - 1;
        int ppos = waveBase + b;
        const float* tp = tslab + (size_t)ppos * 85;
        const float* ypp = yslab + (size_t)ppos * 85;
        float tv1 = tp[lane], yv1 = ypp[lane];           // ch 0..63
        bool has2 = lane < 21;
        float tv2 = 0.f, yv2 = 0.f;
        if (has2) { tv2 = tp[lane + 64]; yv2 = ypp[lane + 64]; }  // ch 64..84

        float tw = __shfl(tv1, 2, 64);
        float th = __shfl(tv1, 3, 64);
        float bs = 2.0f - tw * th;
        int a = ppos % 3, cell = ppos / 3;
        int jj = cell % G, ii = cell / G;
        float aw = anc[a][0], ah = anc[a][1];

        float term;
        if (lane == 0)      term = bs * bce_f(tv1 * (float)G - (float)jj, yv1);
        else if (lane == 1) term = bs * bce_f(tv1 * (float)G - (float)ii, yv1);
        else if (lane == 2) { float d = logf(tv1 * 320.0f / aw) - yv1; term = bs * 0.5f * d * d; }
        else if (lane == 3) { float d = logf(tv1 * 320.0f / ah) - yv1; term = bs * 0.5f * d * d; }
        else if (lane == 4) term = 0.0f;               // conf for positives already in phase B
        else                term = bce_f(tv1, yv1);    // cls 5..63
        if (has2) term += bce_f(tv2, yv2);             // cls 64..84
        acc += term;
    }
    return acc;
}

__global__ __launch_bounds__(256) void k_main(
    const float* __restrict__ t0, const float* __restrict__ y0,
    const float* __restrict__ t1, const float* __restrict__ y1,
    const float* __restrict__ t2, const float* __restrict__ y2,
    const int* __restrict__ counts, const float4* __restrict__ boxes,
    float* __restrict__ partials, int* __restrict__ done,
    float* __restrict__ out)
{
    __shared__ float4 sbox[SCAP];
    int blk = blockIdx.x;

    float acc;
    if (blk < 8) {
        int img = blk >> 1;
        acc = layer_block< 300, 10>(t0, y0, img, blk & 1, CAP0, img * CAP0,
                                    c_anc[0], counts, boxes, sbox, img);
    } else if (blk < 28) {
        int r = blk - 8, img = r / 5;
        acc = layer_block<1200, 20>(t1, y1, img, r % 5, CAP1, 256 + img * CAP1,
                                    c_anc[1], counts, boxes, sbox, 4 + img);
    } else {
        int r = blk - 28, img = r / 19;
        acc = layer_block<4800, 40>(t2, y2, img, r % 19, CAP2, 768 + img * CAP2,
                                    c_anc[2], counts, boxes, sbox, 8 + img);
    }

    // block reduce (4 waves)
    float v = acc;
    #pragma unroll
    for (int o = 32; o > 0; o >>= 1) v += __shfl_down(v, o, 64);
    __shared__ float red[4];
    int lane = threadIdx.x & 63, w = threadIdx.x >> 6;
    if (lane == 0) red[w] = v;
    __syncthreads();

    // last-block-done finalize (done zeroed by k_init this call)
    if (threadIdx.x < 64) {
        int old = 0;
        if (threadIdx.x == 0) {
            float p = ((red[0] + red[1]) + (red[2] + red[3])) * 0.25f;  // mean over B=4
            __hip_atomic_store(&partials[blk], p, __ATOMIC_RELAXED, __HIP_MEMORY_SCOPE_AGENT);
            old = __hip_atomic_fetch_add(done, 1, __ATOMIC_ACQ_REL, __HIP_MEMORY_SCOPE_AGENT);
        }
        old = __shfl(old, 0, 64);
        if (old == NBLK - 1) {
            float s = 0.0f;
            if (lane < NBLK - 64)
                s = __hip_atomic_load(&partials[lane + 64], __ATOMIC_RELAXED, __HIP_MEMORY_SCOPE_AGENT);
            s += __hip_atomic_load(&partials[lane], __ATOMIC_RELAXED, __HIP_MEMORY_SCOPE_AGENT);
            #pragma unroll
            for (int o = 32; o > 0; o >>= 1) s += __shfl_down(s, o, 64);
            if (lane == 0) out[0] = s;
        }
    }
}

extern "C" void kernel_launch(void* const* d_in, const int* in_sizes, int n_in,
                              void* d_out, int out_size, void* d_ws, size_t ws_size,
                              hipStream_t stream) {
    // setup_inputs dict order: t0, y0, t1, y1, t2, y2
    const float* t0 = (const float*)d_in[0];
    const float* y0 = (const float*)d_in[1];
    const float* t1 = (const float*)d_in[2];
    const float* y1 = (const float*)d_in[3];
    const float* t2 = (const float*)d_in[4];
    const float* y2 = (const float*)d_in[5];

    int*    counts   = (int*)d_ws;
    int*    done     = (int*)((char*)d_ws + 64);
    float4* boxes    = (float4*)((char*)d_ws + 128);
    float*  partials = (float*)((char*)d_ws + 45184);
    float*  out      = (float*)d_out;

    k_init<<<1, 64, 0, stream>>>(counts, done);
    k_compact<<<99, 256, 0, stream>>>(t0, t1, t2, counts, boxes);
    k_main<<<NBLK, 256, 0, stream>>>(t0, y0, t1, y1, t2, y2, counts, boxes,
                                     partials, done, out);
}

// Round 10
// 33.303 us; speedup vs baseline: 1.4737x; 1.0283x over previous
//
#include <hip/hip_runtime.h>
#include <math.h>

// B=4, 3 anchors, 85 ch. Layers g=10/20/40 -> P=300/1200/4800 pos/img.
// Single fused kernel, 104 blocks x 256:
//   l0: 2 chunks/img -> blk 0..7   l1: 5 -> blk 8..27   l2: 19 -> blk 28..103
// Wait-free producer/spin consumer: every block compacts its OWN chunk then
// release-increments prog; consumers spin until prog==104 (producers never
// depend on other blocks -> no deadlock under any scheduling).
//
// ws: prog int @0 (memset 0 each call) ; subcnt int[104] @64 ;
//     sublist float4[104*32] @1024 ; partials float[104] @54272
#define NBLK 104
#define SUBCAP 32    // per-256-row-chunk positive cap (E[X]=5.1, P(X>32)~1e-12)
#define SCAP 640     // per-image LDS box capacity (19*32=608 max)

__device__ __constant__ float c_anc[3][3][2] = {
  {{116.f, 90.f}, {156.f, 198.f}, {373.f, 326.f}},
  {{ 30.f, 61.f}, { 62.f,  45.f}, { 59.f, 119.f}},
  {{ 10.f, 13.f}, { 16.f,  30.f}, { 33.f,  23.f}}};

__device__ __forceinline__ float bce_f(float label, float logit) {
    return fmaxf(logit, 0.0f) - logit * label + log1pf(expf(-fabsf(logit)));
}

__global__ __launch_bounds__(256) void k_fused(
    const float* __restrict__ t0, const float* __restrict__ y0,
    const float* __restrict__ t1, const float* __restrict__ y1,
    const float* __restrict__ t2, const float* __restrict__ y2,
    int* __restrict__ prog, int* __restrict__ subcnt,
    float4* __restrict__ sublist, float* __restrict__ partials,
    float* __restrict__ out)
{
    const int blk = blockIdx.x, tid = threadIdx.x;
    int img, chunk, P, G, imgBlkBase, nchunks;
    const float *t, *y; const float (*anc)[2];
    if (blk < 8)       { img = blk >> 1;          chunk = blk & 1;  P = 300;  G = 10; t = t0; y = y0; anc = c_anc[0]; imgBlkBase = img * 2;      nchunks = 2;  }
    else if (blk < 28) { int r = blk - 8;  img = r / 5;  chunk = r % 5;  P = 1200; G = 20; t = t1; y = y1; anc = c_anc[1]; imgBlkBase = 8 + img * 5;  nchunks = 5;  }
    else               { int r = blk - 28; img = r / 19; chunk = r % 19; P = 4800; G = 40; t = t2; y = y2; anc = c_anc[2]; imgBlkBase = 28 + img * 19; nchunks = 19; }

    const float* tslab = t + (size_t)img * P * 85;
    const float* yslab = y + (size_t)img * P * 85;

    // ---- early loads: q operands + own obj (latency hides under compact/spin) ----
    int pos = chunk * 256 + tid;
    bool valid = pos < P;
    int ppre = valid ? pos : 0;
    const float* yp = yslab + (size_t)ppre * 85;
    float q0 = yp[0], q1 = yp[1], q2 = yp[2], q3 = yp[3], q4 = yp[4];
    float obj = tslab[(size_t)ppre * 85 + 4];
    if (!valid) obj = 0.0f;

    // ---- phase 0: compact OWN chunk's positives into this block's sublist ----
    __shared__ int scnt;
    if (tid == 0) scnt = 0;
    __syncthreads();
    int myslot = -1;
    if (valid && obj != 0.0f) myslot = atomicAdd(&scnt, 1);
    if (myslot >= 0 && myslot < SUBCAP) {
        const float* tp = tslab + (size_t)pos * 85;
        float tx = tp[0], ty = tp[1], tw = tp[2], th = tp[3];
        sublist[blk * SUBCAP + myslot] =
            make_float4(tx - tw * 0.5f, ty - th * 0.5f, tx + tw * 0.5f, ty + th * 0.5f);
    }
    __syncthreads();                       // all sublist stores drained (vmcnt) + scnt final
    if (tid == 0) {
        int c = scnt; if (c > SUBCAP) c = SUBCAP;
        subcnt[blk] = c;
        __hip_atomic_fetch_add(prog, 1, __ATOMIC_RELEASE, __HIP_MEMORY_SCOPE_AGENT);
        // spin until all 104 producers published (wait-free producer side)
        while (__hip_atomic_load(prog, __ATOMIC_ACQUIRE, __HIP_MEMORY_SCOPE_AGENT) < NBLK)
            __builtin_amdgcn_s_sleep(2);
    }
    __syncthreads();

    // ---- phase A: gather image's sublists into LDS at exact prefix offsets ----
    __shared__ float4 sbox[SCAP];
    __shared__ int scounts[19], sprefix[20];
    if (tid < nchunks) scounts[tid] = subcnt[imgBlkBase + tid];
    __syncthreads();
    if (tid == 0) {
        int a0 = 0;
        for (int c = 0; c < nchunks; ++c) { sprefix[c] = a0; a0 += scounts[c]; }
        sprefix[nchunks] = a0;
    }
    __syncthreads();
    int total = sprefix[nchunks];
    for (int tp_ = tid; tp_ < nchunks * SUBCAP; tp_ += 256) {
        int c = tp_ >> 5, s = tp_ & 31;
        if (s < scounts[c]) sbox[sprefix[c] + s] = sublist[(imgBlkBase + c) * SUBCAP + s];
    }
    __syncthreads();
    int cntPad = (total + 7) & ~7;         // pad boxes (0,0,0,0): margin = -pa < 0
    for (int k = total + tid; k < cntPad; k += 256)
        sbox[k] = make_float4(0.f, 0.f, 0.f, 0.f);
    __syncthreads();

    // ---- phase B: conf term; division-free ignore (iou>=0.5 <=> 3*inter>=pa+ta) ----
    float acc = 0.0f;
    if (valid) {
        int a = pos % 3, cell = pos / 3;
        int j = cell % G, i = cell / G;
        float aw = anc[a][0], ah = anc[a][1];
        float gi = (float)G;

        float px = (1.0f / (1.0f + expf(-q0)) + (float)j) / gi;
        float py = (1.0f / (1.0f + expf(-q1)) + (float)i) / gi;
        float pw = expf(q2) * aw * (1.0f / 320.0f);
        float ph = expf(q3) * ah * (1.0f / 320.0f);
        float phx = pw * 0.5f, phy = ph * 0.5f;
        float pminx = px - phx, pmaxx = px + phx;
        float pminy = py - phy, pmaxy = py + phy;
        float pa = pw * ph;

        float m = -1.0f;                    // max margin; <0 => ignore
        for (int k0 = 0; k0 < cntPad; k0 += 8) {
            float mm[8];
            #pragma unroll
            for (int u = 0; u < 8; ++u) {
                float4 tb = sbox[k0 + u];   // (minx,miny,maxx,maxy)
                float wx = fminf(pmaxx, tb.z) - fmaxf(pminx, tb.x);
                float wy = fminf(pmaxy, tb.w) - fmaxf(pminy, tb.y);
                wx = fmaxf(wx, 0.0f);
                wy = fmaxf(wy, 0.0f);
                float inter = wx * wy;
                float ta = (tb.z - tb.x) * (tb.w - tb.y);
                mm[u] = 3.0f * inter - pa - ta;
            }
            float a0 = fmaxf(mm[0], mm[1]), a1 = fmaxf(mm[2], mm[3]);
            float a2 = fmaxf(mm[4], mm[5]), a3 = fmaxf(mm[6], mm[7]);
            m = fmaxf(m, fmaxf(fmaxf(a0, a1), fmaxf(a2, a3)));
        }
        float ignore = (m < 0.0f) ? 1.0f : 0.0f;
        float bce_c = fmaxf(q4, 0.0f) - q4 * obj + log1pf(expf(-fabsf(q4)));
        acc = (obj + (1.0f - obj) * ignore) * bce_c;   // gate==1 for positives
    }

    // ---- phase C: positives, whole-wave per-channel (coalesced rows) ----
    unsigned long long mb = __ballot(valid && obj != 0.0f);
    int lane = tid & 63;
    int waveBase = chunk * 256 + (tid & ~63);
    while (mb) {
        int b = __ffsll(mb) - 1; mb &= mb - 1;
        int ppos = waveBase + b;
        const float* tp = tslab + (size_t)ppos * 85;
        const float* ypp = yslab + (size_t)ppos * 85;
        float tv1 = tp[lane], yv1 = ypp[lane];           // ch 0..63
        bool has2 = lane < 21;
        float tv2 = 0.f, yv2 = 0.f;
        if (has2) { tv2 = tp[lane + 64]; yv2 = ypp[lane + 64]; }  // ch 64..84

        float tw = __shfl(tv1, 2, 64);
        float th = __shfl(tv1, 3, 64);
        float bs = 2.0f - tw * th;
        int a = ppos % 3, cell = ppos / 3;
        int jj = cell % G, ii = cell / G;
        float aw = anc[a][0], ah = anc[a][1];

        float term;
        if (lane == 0)      term = bs * bce_f(tv1 * (float)G - (float)jj, yv1);
        else if (lane == 1) term = bs * bce_f(tv1 * (float)G - (float)ii, yv1);
        else if (lane == 2) { float d = logf(tv1 * 320.0f / aw) - yv1; term = bs * 0.5f * d * d; }
        else if (lane == 3) { float d = logf(tv1 * 320.0f / ah) - yv1; term = bs * 0.5f * d * d; }
        else if (lane == 4) term = 0.0f;               // conf for positives already in phase B
        else                term = bce_f(tv1, yv1);    // cls 5..63
        if (has2) term += bce_f(tv2, yv2);             // cls 64..84
        acc += term;
    }

    // ---- block reduce + last-block finalize (prog counts 104 -> 208) ----
    float v = acc;
    #pragma unroll
    for (int o = 32; o > 0; o >>= 1) v += __shfl_down(v, o, 64);
    __shared__ float red[4];
    int w = tid >> 6;
    if (lane == 0) red[w] = v;
    __syncthreads();

    if (tid < 64) {
        int old = 0;
        if (tid == 0) {
            float p = ((red[0] + red[1]) + (red[2] + red[3])) * 0.25f;  // mean over B=4
            __hip_atomic_store(&partials[blk], p, __ATOMIC_RELAXED, __HIP_MEMORY_SCOPE_AGENT);
            old = __hip_atomic_fetch_add(prog, 1, __ATOMIC_ACQ_REL, __HIP_MEMORY_SCOPE_AGENT);
        }
        old = __shfl(old, 0, 64);
        if (old == 2 * NBLK - 1) {
            float s = 0.0f;
            if (lane < NBLK - 64)
                s = __hip_atomic_load(&partials[lane + 64], __ATOMIC_RELAXED, __HIP_MEMORY_SCOPE_AGENT);
            s += __hip_atomic_load(&partials[lane], __ATOMIC_RELAXED, __HIP_MEMORY_SCOPE_AGENT);
            #pragma unroll
            for (int o = 32; o > 0; o >>= 1) s += __shfl_down(s, o, 64);
            if (lane == 0) out[0] = s;
        }
    }
}

extern "C" void kernel_launch(void* const* d_in, const int* in_sizes, int n_in,
                              void* d_out, int out_size, void* d_ws, size_t ws_size,
                              hipStream_t stream) {
    // setup_inputs dict order: t0, y0, t1, y1, t2, y2
    const float* t0 = (const float*)d_in[0];
    const float* y0 = (const float*)d_in[1];
    const float* t1 = (const float*)d_in[2];
    const float* y1 = (const float*)d_in[3];
    const float* t2 = (const float*)d_in[4];
    const float* y2 = (const float*)d_in[5];

    int*    prog     = (int*)d_ws;
    int*    subcnt   = (int*)((char*)d_ws + 64);
    float4* sublist  = (float4*)((char*)d_ws + 1024);
    float*  partials = (float*)((char*)d_ws + 54272);
    float*  out      = (float*)d_out;

    hipMemsetAsync(prog, 0, sizeof(int), stream);   // single tiny memset node
    k_fused<<<NBLK, 256, 0, stream>>>(t0, y0, t1, y1, t2, y2,
                                      prog, subcnt, sublist, partials, out);
}